// Round 5
// baseline (450.218 us; speedup 1.0000x reference)
//
#include <hip/hip_runtime.h>
#include <hip/hip_bf16.h>
#include <cstdint>

#define NC 28
#define HW 65536   // 256*256
#define ROWW 256
#define COLW 310
#define BATCH 16

typedef __hip_bfloat16 bf16;

__device__ __forceinline__ float bflo(unsigned int u) { return __uint_as_float(u << 16); }
__device__ __forceinline__ float bfhi(unsigned int u) { return __uint_as_float(u & 0xffff0000u); }
__device__ __forceinline__ float sgpr(float x) {
    return __int_as_float(__builtin_amdgcn_readfirstlane(__float_as_int(x)));
}
__device__ __forceinline__ unsigned int pk2(float lo, float hi) {
    unsigned short l = __builtin_bit_cast(unsigned short, __float2bfloat16(lo));
    unsigned short h = __builtin_bit_cast(unsigned short, __float2bfloat16(hi));
    return (unsigned int)l | ((unsigned int)h << 16);
}
__device__ __forceinline__ float2 upk(unsigned int u) {
    return make_float2(__uint_as_float(u << 16), __uint_as_float(u & 0xffff0000u));
}
// packed 2xf32 fma: acc = w*x + acc  (one VALU inst for both branches; w in SGPR pair)
__device__ __forceinline__ void pkfma(float2& acc, const float2& w, const float2& x) {
    asm("v_pk_fma_f32 %0, %1, %2, %0" : "+v"(acc) : "s"(w), "v"(x));
}

// hdr layout (floats):
//   [0      .. 1567]  w1pair[c][o]  = (w1mm[o][c], w1pv[o][c])   interleaved float2
//   [1568   .. 3135]  w2pair[o][m]  = (w2mm[o][m], w2pv[o][m])   interleaved float2
//   [3136   .. 3191]  b1pair[o]     = (b1mm[o], b1pv[o])
//   [3192   .. 3247]  b2pair[o]     = (b2mm[o], b2pv[o])
//   [3248   .. 3557]  alpha[col]
#define HDR_BYTES 16384

// ---------------- K0: prep — interleave weight pairs, compute alpha ----------------
__global__ void k0_prep(const float* __restrict__ w1mm, const float* __restrict__ w1pv,
                        const float* __restrict__ w2mm, const float* __restrict__ w2pv,
                        const float* __restrict__ b1mm, const float* __restrict__ b1pv,
                        const float* __restrict__ b2mm, const float* __restrict__ b2pv,
                        float* __restrict__ hdr)
{
    int t = threadIdx.x;
    for (int e = t; e < 784; e += 256) {
        int c = e / 28, o = e - c * 28;
        hdr[2 * e]     = w1mm[o * 28 + c];      // w1pair[c][o].x
        hdr[2 * e + 1] = w1pv[o * 28 + c];      // w1pair[c][o].y
        hdr[1568 + 2 * e]     = w2mm[e];        // w2pair[o][m].x  (e = o*28+m)
        hdr[1568 + 2 * e + 1] = w2pv[e];
    }
    if (t < 28) {
        hdr[3136 + 2 * t]     = b1mm[t];
        hdr[3136 + 2 * t + 1] = b1pv[t];
        hdr[3192 + 2 * t]     = b2mm[t];
        hdr[3192 + 2 * t + 1] = b2pv[t];
    }
    for (int col = t; col < COLW; col += 256) {
        int imin = (col > 255) ? ((col - 254) >> 1) : 0;
        int imax = min(27, col >> 1);
        hdr[3248 + col] = 1.0f / (float)(imax - imin + 1);
    }
}

// ---------------- K1: conv1x1 x2 both branches, fully packed pk_fma ----------------
__global__ __launch_bounds__(256) void k1_conv1x1(
    const float* __restrict__ Phi, const float* __restrict__ hdr,
    unsigned int* __restrict__ t_pk, unsigned int* __restrict__ m1_pk)
{
    int idx = blockIdx.x * 256 + threadIdx.x;   // 0 .. 1048575
    int b  = idx >> 16;                          // HW = 2^16
    int hw = idx & (HW - 1);
    const float*  phi = Phi + (size_t)b * NC * HW + hw;
    const float2* w1p = (const float2*)hdr;             // [c*28+o]
    const float2* w2p = (const float2*)(hdr + 1568);    // [o*28+m]
    const float2* b1p = (const float2*)(hdr + 3136);
    const float2* b2p = (const float2*)(hdr + 3192);

    float2 m1[NC];
#pragma unroll
    for (int o = 0; o < NC; o++) m1[o] = b1p[o];

    for (int c = 0; c < NC; c++) {
        float p = phi[(size_t)c * HW];
        float2 pp = make_float2(p, p);
        const float2* wr = w1p + c * NC;
#pragma unroll
        for (int o = 0; o < NC; o++) pkfma(m1[o], wr[o], pp);
    }

    float2 tt[NC];
#pragma unroll
    for (int o = 0; o < NC; o++) tt[o] = b2p[o];

    for (int o = 0; o < NC; o++) {
        const float2* wr = w2p + o * NC;
        float2 acc = tt[o];
#pragma unroll
        for (int m = 0; m < NC; m++) pkfma(acc, wr[m], m1[m]);
        tt[o] = acc;
    }

    size_t base = (size_t)b * NC * HW + hw;
#pragma unroll
    for (int o = 0; o < NC; o++) {
        size_t off = base + (size_t)o * HW;
        t_pk[off]  = pk2(tt[o].x, tt[o].y);
        m1_pk[off] = pk2(m1[o].x, m1[o].y);
    }
}

// ---------------- K2: dwconv5 + sigmoid + emb + where; pk_fma, window in float2 regs ----------------
#define TR 16
#define LROW 264   // words per LDS row; interior at [4..259], pads [2,3] and [260,261]; 16B-aligned

#define LDROW(S, LR) do { \
    const unsigned int* rp_ = &st[(LR) * LROW + 2 + w]; \
    unsigned int u0_=rp_[0], u1_=rp_[1], u2_=rp_[2], u3_=rp_[3], u4_=rp_[4]; \
    W##S##0 = upk(u0_); W##S##1 = upk(u1_); W##S##2 = upk(u2_); \
    W##S##3 = upk(u3_); W##S##4 = upk(u4_); \
} while(0)

#define TAP5(S, B) \
    pkfma(acc, wq[(B)+0], W##S##0); \
    pkfma(acc, wq[(B)+1], W##S##1); \
    pkfma(acc, wq[(B)+2], W##S##2); \
    pkfma(acc, wq[(B)+3], W##S##3); \
    pkfma(acc, wq[(B)+4], W##S##4);

#define CROW(R, S0,S1,S2,S3,S4) do { \
    size_t off_ = cbase + (size_t)(r0 + (R)) * 256 + w; \
    unsigned int mu_ = m1_pk[off_]; \
    float xp_ = x_pre[off_]; \
    float2 acc = make_float2(dbmc, dbpc); \
    TAP5(S0, 0) TAP5(S1, 5) TAP5(S2, 10) TAP5(S3, 15) TAP5(S4, 20) \
    float attm = __builtin_amdgcn_rcpf(1.f + __expf(-acc.x)); \
    float attp = __builtin_amdgcn_rcpf(1.f + __expf(-acc.y)); \
    float m1m_ = bflo(mu_), m1p_ = bfhi(mu_); \
    float embm_ = fmaf(m1m_, attm, m1m_); \
    float embp_ = fmaf(m1p_, attp, m1p_); \
    if (embm_ == 0.f) embm_ = 1e-6f; \
    if (embp_ == 0.f) embp_ = 1e-6f; \
    z[off_]      = __float2bfloat16(xp_ * embm_); \
    philpv[off_] = __float2bfloat16(embp_); \
} while(0)

__global__ __launch_bounds__(256, 4) void k2_attn(
    const unsigned int* __restrict__ t_pk, const unsigned int* __restrict__ m1_pk,
    const float* __restrict__ x_pre,
    const float* __restrict__ dwm, const float* __restrict__ dbm,
    const float* __restrict__ dwp, const float* __restrict__ dbp,
    bf16* __restrict__ z, bf16* __restrict__ philpv)
{
    __shared__ unsigned int st[(TR + 4) * LROW];   // 20*264*4 = 21,120 B

    int bid = blockIdx.x;
    int rt = bid & 15;
    int c  = (bid >> 4) % NC;
    int b  = (bid >> 4) / NC;
    int r0 = rt * TR;
    size_t cbase = ((size_t)b * NC + c) * HW;
    int tid = threadIdx.x;
    int lane = tid & 63;
    int wv = tid >> 6;

    if (tid < 80) {
        int rr = tid >> 2, jj = tid & 3;
        st[rr * LROW + ((jj < 2) ? 2 + jj : 258 + jj)] = 0u;
    }

#pragma unroll
    for (int j = 0; j < 5; j++) {
        int r = wv * 5 + j;
        int gr = r0 - 2 + r;
        if (gr >= 0 && gr < 256) {
            const unsigned int* gsrc = t_pk + cbase + (size_t)gr * 256 + lane * 4;
            __builtin_amdgcn_global_load_lds(
                (const __attribute__((address_space(1))) unsigned int*)gsrc,
                (__attribute__((address_space(3))) unsigned int*)&st[r * LROW + 4],
                16, 0, 0);
        } else {
            st[r * LROW + 4 + lane]       = 0u;
            st[r * LROW + 4 + 64 + lane]  = 0u;
            st[r * LROW + 4 + 128 + lane] = 0u;
            st[r * LROW + 4 + 192 + lane] = 0u;
        }
    }

    float2 wq[25];
#pragma unroll
    for (int k = 0; k < 25; k++)
        wq[k] = make_float2(sgpr(dwm[c * 25 + k]), sgpr(dwp[c * 25 + k]));
    float dbmc = sgpr(dbm[c]), dbpc = sgpr(dbp[c]);

    __syncthreads();

    int w = tid;   // output column 0..255
    float2 W00,W01,W02,W03,W04, W10,W11,W12,W13,W14, W20,W21,W22,W23,W24,
           W30,W31,W32,W33,W34, W40,W41,W42,W43,W44;

    LDROW(0,0); LDROW(1,1); LDROW(2,2); LDROW(3,3);
    LDROW(4,4);  CROW(0, 0,1,2,3,4);
    LDROW(0,5);  CROW(1, 1,2,3,4,0);
    LDROW(1,6);  CROW(2, 2,3,4,0,1);
    LDROW(2,7);  CROW(3, 3,4,0,1,2);
    LDROW(3,8);  CROW(4, 4,0,1,2,3);
    LDROW(4,9);  CROW(5, 0,1,2,3,4);
    LDROW(0,10); CROW(6, 1,2,3,4,0);
    LDROW(1,11); CROW(7, 2,3,4,0,1);
    LDROW(2,12); CROW(8, 3,4,0,1,2);
    LDROW(3,13); CROW(9, 4,0,1,2,3);
    LDROW(4,14); CROW(10, 0,1,2,3,4);
    LDROW(0,15); CROW(11, 1,2,3,4,0);
    LDROW(1,16); CROW(12, 2,3,4,0,1);
    LDROW(2,17); CROW(13, 3,4,0,1,2);
    LDROW(3,18); CROW(14, 4,0,1,2,3);
    LDROW(4,19); CROW(15, 0,1,2,3,4);
}

// ---------------- K3: temp = alpha * (y - A_op partial sums) ----------------
__global__ void k3_aop(const float* __restrict__ y, const bf16* __restrict__ z,
                       const float* __restrict__ alpha, float* __restrict__ temp)
{
    int idx = blockIdx.x * 256 + threadIdx.x;
    if (idx >= BATCH * ROWW * COLW) return;
    int col = idx % COLW;
    int bh  = idx / COLW;
    int h = bh & 255;
    int b = bh >> 8;
    int imin = (col > 255) ? ((col - 254) >> 1) : 0;
    int imax = min(27, col >> 1);
    float acc = y[idx];
    size_t base = (size_t)b * NC * HW + (size_t)h * 256 + col;
    for (int i = imin; i <= imax; i++) {
        acc -= __bfloat162float(z[base + (size_t)i * (HW - 2)]);
    }
    temp[idx] = acc * alpha[col];
}

// ---------------- K4: out = x_pre + delta * temp_gathered * PhiL_pv (x4 vectorized) ----------------
__global__ void k4_out(const float* __restrict__ x_pre, const bf16* __restrict__ philpv,
                       const float* __restrict__ temp, const float* __restrict__ delta,
                       float* __restrict__ out)
{
    int idx4 = blockIdx.x * 256 + threadIdx.x;   // quad index; exact grid
    int wq4 = idx4 & 63;
    int rest = idx4 >> 6;
    int h = rest & 255; rest >>= 8;
    int i = rest % NC;
    int b = rest / NC;
    int w = wq4 * 4;
    int col = w + 2 * i;
    const float* trow = temp + ((size_t)(b * 256 + h)) * COLW + col;
    float t0 = trow[0], t1 = trow[1], t2 = trow[2], t3 = trow[3];
    size_t off = ((size_t)(b * NC + i)) * HW + (size_t)(h * 256 + w);
    uint2 pu = *reinterpret_cast<const uint2*>(philpv + off);
    float4 xp = *reinterpret_cast<const float4*>(x_pre + off);
    float d = delta[0];
    float4 o4;
    o4.x = fmaf(d * t0, bflo(pu.x), xp.x);
    o4.y = fmaf(d * t1, bfhi(pu.x), xp.y);
    o4.z = fmaf(d * t2, bflo(pu.y), xp.z);
    o4.w = fmaf(d * t3, bfhi(pu.y), xp.w);
    *reinterpret_cast<float4*>(out + off) = o4;
}

// ---------------- launch ----------------
extern "C" void kernel_launch(void* const* d_in, const int* in_sizes, int n_in,
                              void* d_out, int out_size, void* d_ws, size_t ws_size,
                              hipStream_t stream)
{
    const float* y     = (const float*)d_in[0];
    const float* Phi   = (const float*)d_in[1];
    const float* x_pre = (const float*)d_in[2];
    const float* delta = (const float*)d_in[3];
    const float* mm_w1 = (const float*)d_in[4];
    const float* mm_b1 = (const float*)d_in[5];
    const float* mm_w2 = (const float*)d_in[6];
    const float* mm_b2 = (const float*)d_in[7];
    const float* mm_dw = (const float*)d_in[8];
    const float* mm_db = (const float*)d_in[9];
    const float* pv_w1 = (const float*)d_in[10];
    const float* pv_b1 = (const float*)d_in[11];
    const float* pv_w2 = (const float*)d_in[12];
    const float* pv_b2 = (const float*)d_in[13];
    const float* pv_dw = (const float*)d_in[14];
    const float* pv_db = (const float*)d_in[15];
    float* out = (float*)d_out;

    char* ws = (char*)d_ws;
    const size_t A = (size_t)BATCH * NC * HW * 4;   // 117,440,512 B (uint array)
    float*        hdr    = (float*)ws;
    unsigned int* t_pk   = (unsigned int*)(ws + HDR_BYTES);
    unsigned int* m1_pk  = (unsigned int*)(ws + HDR_BYTES + A);
    bf16*         zz     = (bf16*)(ws + HDR_BYTES + 2 * A);
    bf16*         philpv = (bf16*)(ws + HDR_BYTES + 2 * A + A / 2);
    float*        temp   = (float*)(ws + HDR_BYTES + 3 * A);

    k0_prep<<<1, 256, 0, stream>>>(mm_w1, pv_w1, mm_w2, pv_w2,
                                   mm_b1, pv_b1, mm_b2, pv_b2, hdr);
    k1_conv1x1<<<4096, 256, 0, stream>>>(Phi, hdr, t_pk, m1_pk);
    k2_attn<<<BATCH * NC * (256 / TR), 256, 0, stream>>>(t_pk, m1_pk, x_pre,
                                                         mm_dw, mm_db, pv_dw, pv_db, zz, philpv);
    k3_aop<<<(BATCH * ROWW * COLW + 255) / 256, 256, 0, stream>>>(y, zz, hdr + 3248, temp);
    k4_out<<<(BATCH * NC * HW / 4) / 256, 256, 0, stream>>>(x_pre, philpv, temp, delta, out);
}

// Round 6
// 299.885 us; speedup vs baseline: 1.5013x; 1.5013x over previous
//
#include <hip/hip_runtime.h>
#include <hip/hip_bf16.h>
#include <cstdint>

#define NC 28
#define HW 65536   // 256*256
#define ROWW 256
#define COLW 310
#define BATCH 16

typedef __hip_bfloat16 bf16;

__device__ __forceinline__ float bflo(unsigned int u) { return __uint_as_float(u << 16); }
__device__ __forceinline__ float bfhi(unsigned int u) { return __uint_as_float(u & 0xffff0000u); }
__device__ __forceinline__ float sgpr(float x) {
    return __int_as_float(__builtin_amdgcn_readfirstlane(__float_as_int(x)));
}
__device__ __forceinline__ unsigned int pk2(float lo, float hi) {
    unsigned short l = __builtin_bit_cast(unsigned short, __float2bfloat16(lo));
    unsigned short h = __builtin_bit_cast(unsigned short, __float2bfloat16(hi));
    return (unsigned int)l | ((unsigned int)h << 16);
}
__device__ __forceinline__ float2 upk(unsigned int u) {
    return make_float2(__uint_as_float(u << 16), __uint_as_float(u & 0xffff0000u));
}
// packed 2xf32 fma: acc = w*x + acc  (one VALU inst for both branches; w in SGPR pair)
__device__ __forceinline__ void pkfma(float2& acc, const float2& w, const float2& x) {
    asm("v_pk_fma_f32 %0, %1, %2, %0" : "+v"(acc) : "s"(w), "v"(x));
}

#define REP28(X) X(0) X(1) X(2) X(3) X(4) X(5) X(6) X(7) X(8) X(9) X(10) X(11) X(12) X(13) \
                 X(14) X(15) X(16) X(17) X(18) X(19) X(20) X(21) X(22) X(23) X(24) X(25) X(26) X(27)

// hdr layout (floats):
//   [0      .. 1567]  w1pair[c][o]  = (w1mm[o][c], w1pv[o][c])   interleaved float2
//   [1568   .. 3135]  w2pair[o][m]  = (w2mm[o][m], w2pv[o][m])   interleaved float2
//   [3136   .. 3191]  b1pair[o]     = (b1mm[o], b1pv[o])
//   [3192   .. 3247]  b2pair[o]     = (b2mm[o], b2pv[o])
//   [3248   .. 3557]  alpha[col]
#define HDR_BYTES 16384

// ---------------- K0: prep — interleave weight pairs, compute alpha ----------------
__global__ void k0_prep(const float* __restrict__ w1mm, const float* __restrict__ w1pv,
                        const float* __restrict__ w2mm, const float* __restrict__ w2pv,
                        const float* __restrict__ b1mm, const float* __restrict__ b1pv,
                        const float* __restrict__ b2mm, const float* __restrict__ b2pv,
                        float* __restrict__ hdr)
{
    int t = threadIdx.x;
    for (int e = t; e < 784; e += 256) {
        int c = e / 28, o = e - c * 28;
        hdr[2 * e]     = w1mm[o * 28 + c];      // w1pair[c][o].x
        hdr[2 * e + 1] = w1pv[o * 28 + c];      // w1pair[c][o].y
        hdr[1568 + 2 * e]     = w2mm[e];        // w2pair[o][m].x  (e = o*28+m)
        hdr[1568 + 2 * e + 1] = w2pv[e];
    }
    if (t < 28) {
        hdr[3136 + 2 * t]     = b1mm[t];
        hdr[3136 + 2 * t + 1] = b1pv[t];
        hdr[3192 + 2 * t]     = b2mm[t];
        hdr[3192 + 2 * t + 1] = b2pv[t];
    }
    for (int col = t; col < COLW; col += 256) {
        int imin = (col > 255) ? ((col - 254) >> 1) : 0;
        int imax = min(27, col >> 1);
        hdr[3248 + col] = 1.0f / (float)(imax - imin + 1);
    }
}

// ---------------- K1: conv1x1 x2 both branches; NAMED float2 accumulators ----------------
__global__ __launch_bounds__(256, 4) void k1_conv1x1(
    const float* __restrict__ Phi, const float* __restrict__ hdr,
    unsigned int* __restrict__ t_pk, unsigned int* __restrict__ m1_pk)
{
    int idx = blockIdx.x * 256 + threadIdx.x;   // 0 .. 1048575
    int b  = idx >> 16;                          // HW = 2^16
    int hw = idx & (HW - 1);
    const float*  phi = Phi + (size_t)b * NC * HW + hw;
    const float2* w1p = (const float2*)hdr;             // [c*28+o]
    const float2* w2p = (const float2*)(hdr + 1568);    // [o*28+m]
    const float2* b1p = (const float2*)(hdr + 3136);
    const float2* b2p = (const float2*)(hdr + 3192);

    // 28 named packed accumulators (mm in .x, pv in .y) — never an array
#define DECL_M(i) float2 M##i = b1p[i];
    REP28(DECL_M)
#undef DECL_M

    for (int c = 0; c < NC; c++) {
        float p = phi[(size_t)c * HW];
        float2 pp = make_float2(p, p);
        const float2* wr = w1p + c * NC;
#define FMA_M(i) pkfma(M##i, wr[i], pp);
        REP28(FMA_M)
#undef FMA_M
    }

    size_t base = (size_t)b * NC * HW + hw;
    // write m1 (packed bf16 pair)
#define ST_M(i) m1_pk[base + (size_t)(i) * HW] = pk2(M##i.x, M##i.y);
    REP28(ST_M)
#undef ST_M

    // stage 2: one named accumulator per output, stored immediately
    for (int o = 0; o < NC; o++) {
        const float2* wr = w2p + o * NC;
        float2 T = b2p[o];
#define FMA_T(i) pkfma(T, wr[i], M##i);
        REP28(FMA_T)
#undef FMA_T
        t_pk[base + (size_t)o * HW] = pk2(T.x, T.y);
    }
}

// ---------------- K2: dwconv5 + sigmoid + emb + where; pk_fma, window in float2 regs ----------------
#define TR 16
#define LROW 264   // words per LDS row; interior at [4..259], pads [2,3] and [260,261]; 16B-aligned

#define LDROW(S, LR) do { \
    const unsigned int* rp_ = &st[(LR) * LROW + 2 + w]; \
    unsigned int u0_=rp_[0], u1_=rp_[1], u2_=rp_[2], u3_=rp_[3], u4_=rp_[4]; \
    W##S##0 = upk(u0_); W##S##1 = upk(u1_); W##S##2 = upk(u2_); \
    W##S##3 = upk(u3_); W##S##4 = upk(u4_); \
} while(0)

#define TAP5(S, B) \
    pkfma(acc, wq[(B)+0], W##S##0); \
    pkfma(acc, wq[(B)+1], W##S##1); \
    pkfma(acc, wq[(B)+2], W##S##2); \
    pkfma(acc, wq[(B)+3], W##S##3); \
    pkfma(acc, wq[(B)+4], W##S##4);

#define CROW(R, S0,S1,S2,S3,S4) do { \
    size_t off_ = cbase + (size_t)(r0 + (R)) * 256 + w; \
    unsigned int mu_ = m1_pk[off_]; \
    float xp_ = x_pre[off_]; \
    float2 acc = make_float2(dbmc, dbpc); \
    TAP5(S0, 0) TAP5(S1, 5) TAP5(S2, 10) TAP5(S3, 15) TAP5(S4, 20) \
    float attm = __builtin_amdgcn_rcpf(1.f + __expf(-acc.x)); \
    float attp = __builtin_amdgcn_rcpf(1.f + __expf(-acc.y)); \
    float m1m_ = bflo(mu_), m1p_ = bfhi(mu_); \
    float embm_ = fmaf(m1m_, attm, m1m_); \
    float embp_ = fmaf(m1p_, attp, m1p_); \
    if (embm_ == 0.f) embm_ = 1e-6f; \
    if (embp_ == 0.f) embp_ = 1e-6f; \
    z[off_]      = __float2bfloat16(xp_ * embm_); \
    philpv[off_] = __float2bfloat16(embp_); \
} while(0)

__global__ __launch_bounds__(256, 4) void k2_attn(
    const unsigned int* __restrict__ t_pk, const unsigned int* __restrict__ m1_pk,
    const float* __restrict__ x_pre,
    const float* __restrict__ dwm, const float* __restrict__ dbm,
    const float* __restrict__ dwp, const float* __restrict__ dbp,
    bf16* __restrict__ z, bf16* __restrict__ philpv)
{
    __shared__ unsigned int st[(TR + 4) * LROW];   // 20*264*4 = 21,120 B

    int bid = blockIdx.x;
    int rt = bid & 15;
    int c  = (bid >> 4) % NC;
    int b  = (bid >> 4) / NC;
    int r0 = rt * TR;
    size_t cbase = ((size_t)b * NC + c) * HW;
    int tid = threadIdx.x;
    int lane = tid & 63;
    int wv = tid >> 6;

    if (tid < 80) {
        int rr = tid >> 2, jj = tid & 3;
        st[rr * LROW + ((jj < 2) ? 2 + jj : 258 + jj)] = 0u;
    }

#pragma unroll
    for (int j = 0; j < 5; j++) {
        int r = wv * 5 + j;
        int gr = r0 - 2 + r;
        if (gr >= 0 && gr < 256) {
            const unsigned int* gsrc = t_pk + cbase + (size_t)gr * 256 + lane * 4;
            __builtin_amdgcn_global_load_lds(
                (const __attribute__((address_space(1))) unsigned int*)gsrc,
                (__attribute__((address_space(3))) unsigned int*)&st[r * LROW + 4],
                16, 0, 0);
        } else {
            st[r * LROW + 4 + lane]       = 0u;
            st[r * LROW + 4 + 64 + lane]  = 0u;
            st[r * LROW + 4 + 128 + lane] = 0u;
            st[r * LROW + 4 + 192 + lane] = 0u;
        }
    }

    float2 wq[25];
#pragma unroll
    for (int k = 0; k < 25; k++)
        wq[k] = make_float2(sgpr(dwm[c * 25 + k]), sgpr(dwp[c * 25 + k]));
    float dbmc = sgpr(dbm[c]), dbpc = sgpr(dbp[c]);

    __syncthreads();

    int w = tid;   // output column 0..255
    float2 W00,W01,W02,W03,W04, W10,W11,W12,W13,W14, W20,W21,W22,W23,W24,
           W30,W31,W32,W33,W34, W40,W41,W42,W43,W44;

    LDROW(0,0); LDROW(1,1); LDROW(2,2); LDROW(3,3);
    LDROW(4,4);  CROW(0, 0,1,2,3,4);
    LDROW(0,5);  CROW(1, 1,2,3,4,0);
    LDROW(1,6);  CROW(2, 2,3,4,0,1);
    LDROW(2,7);  CROW(3, 3,4,0,1,2);
    LDROW(3,8);  CROW(4, 4,0,1,2,3);
    LDROW(4,9);  CROW(5, 0,1,2,3,4);
    LDROW(0,10); CROW(6, 1,2,3,4,0);
    LDROW(1,11); CROW(7, 2,3,4,0,1);
    LDROW(2,12); CROW(8, 3,4,0,1,2);
    LDROW(3,13); CROW(9, 4,0,1,2,3);
    LDROW(4,14); CROW(10, 0,1,2,3,4);
    LDROW(0,15); CROW(11, 1,2,3,4,0);
    LDROW(1,16); CROW(12, 2,3,4,0,1);
    LDROW(2,17); CROW(13, 3,4,0,1,2);
    LDROW(3,18); CROW(14, 4,0,1,2,3);
    LDROW(4,19); CROW(15, 0,1,2,3,4);
}

// ---------------- K3: temp = alpha * (y - A_op partial sums) ----------------
__global__ void k3_aop(const float* __restrict__ y, const bf16* __restrict__ z,
                       const float* __restrict__ alpha, float* __restrict__ temp)
{
    int idx = blockIdx.x * 256 + threadIdx.x;
    if (idx >= BATCH * ROWW * COLW) return;
    int col = idx % COLW;
    int bh  = idx / COLW;
    int h = bh & 255;
    int b = bh >> 8;
    int imin = (col > 255) ? ((col - 254) >> 1) : 0;
    int imax = min(27, col >> 1);
    float acc = y[idx];
    size_t base = (size_t)b * NC * HW + (size_t)h * 256 + col;
    for (int i = imin; i <= imax; i++) {
        acc -= __bfloat162float(z[base + (size_t)i * (HW - 2)]);
    }
    temp[idx] = acc * alpha[col];
}

// ---------------- K4: out = x_pre + delta * temp_gathered * PhiL_pv (x4 vectorized) ----------------
__global__ void k4_out(const float* __restrict__ x_pre, const bf16* __restrict__ philpv,
                       const float* __restrict__ temp, const float* __restrict__ delta,
                       float* __restrict__ out)
{
    int idx4 = blockIdx.x * 256 + threadIdx.x;   // quad index; exact grid
    int wq4 = idx4 & 63;
    int rest = idx4 >> 6;
    int h = rest & 255; rest >>= 8;
    int i = rest % NC;
    int b = rest / NC;
    int w = wq4 * 4;
    int col = w + 2 * i;
    const float* trow = temp + ((size_t)(b * 256 + h)) * COLW + col;
    float t0 = trow[0], t1 = trow[1], t2 = trow[2], t3 = trow[3];
    size_t off = ((size_t)(b * NC + i)) * HW + (size_t)(h * 256 + w);
    uint2 pu = *reinterpret_cast<const uint2*>(philpv + off);
    float4 xp = *reinterpret_cast<const float4*>(x_pre + off);
    float d = delta[0];
    float4 o4;
    o4.x = fmaf(d * t0, bflo(pu.x), xp.x);
    o4.y = fmaf(d * t1, bfhi(pu.x), xp.y);
    o4.z = fmaf(d * t2, bflo(pu.y), xp.z);
    o4.w = fmaf(d * t3, bfhi(pu.y), xp.w);
    *reinterpret_cast<float4*>(out + off) = o4;
}

// ---------------- launch ----------------
extern "C" void kernel_launch(void* const* d_in, const int* in_sizes, int n_in,
                              void* d_out, int out_size, void* d_ws, size_t ws_size,
                              hipStream_t stream)
{
    const float* y     = (const float*)d_in[0];
    const float* Phi   = (const float*)d_in[1];
    const float* x_pre = (const float*)d_in[2];
    const float* delta = (const float*)d_in[3];
    const float* mm_w1 = (const float*)d_in[4];
    const float* mm_b1 = (const float*)d_in[5];
    const float* mm_w2 = (const float*)d_in[6];
    const float* mm_b2 = (const float*)d_in[7];
    const float* mm_dw = (const float*)d_in[8];
    const float* mm_db = (const float*)d_in[9];
    const float* pv_w1 = (const float*)d_in[10];
    const float* pv_b1 = (const float*)d_in[11];
    const float* pv_w2 = (const float*)d_in[12];
    const float* pv_b2 = (const float*)d_in[13];
    const float* pv_dw = (const float*)d_in[14];
    const float* pv_db = (const float*)d_in[15];
    float* out = (float*)d_out;

    char* ws = (char*)d_ws;
    const size_t A = (size_t)BATCH * NC * HW * 4;   // 117,440,512 B (uint array)
    float*        hdr    = (float*)ws;
    unsigned int* t_pk   = (unsigned int*)(ws + HDR_BYTES);
    unsigned int* m1_pk  = (unsigned int*)(ws + HDR_BYTES + A);
    bf16*         zz     = (bf16*)(ws + HDR_BYTES + 2 * A);
    bf16*         philpv = (bf16*)(ws + HDR_BYTES + 2 * A + A / 2);
    float*        temp   = (float*)(ws + HDR_BYTES + 3 * A);

    k0_prep<<<1, 256, 0, stream>>>(mm_w1, pv_w1, mm_w2, pv_w2,
                                   mm_b1, pv_b1, mm_b2, pv_b2, hdr);
    k1_conv1x1<<<4096, 256, 0, stream>>>(Phi, hdr, t_pk, m1_pk);
    k2_attn<<<BATCH * NC * (256 / TR), 256, 0, stream>>>(t_pk, m1_pk, x_pre,
                                                         mm_dw, mm_db, pv_dw, pv_db, zz, philpv);
    k3_aop<<<(BATCH * ROWW * COLW + 255) / 256, 256, 0, stream>>>(y, zz, hdr + 3248, temp);
    k4_out<<<(BATCH * NC * HW / 4) / 256, 256, 0, stream>>>(x_pre, philpv, temp, delta, out);
}